// Round 1
// baseline (86.093 us; speedup 1.0000x reference)
//
#include <hip/hip_runtime.h>

// ClassCaps vote transform:
//   votes[b,h,w,i,o,m,p] = sum_n poses[b,h,w,i,m,n] * weight[i,o,n,p]
//                          + (m==0&&p==3 ? xv[h,w] : 0) + (m==1&&p==3 ? yv[h,w] : 0)
// Outputs (concatenated in d_out): votes [B*H*W*CIN*COUT*16] fp32, acts [B*H*W*CIN] fp32.

namespace {
constexpr int kB = 64, kH = 14, kW = 14, kCIN = 32, kCOUT = 10;
constexpr int kSITES = kB * kH * kW * kCIN;        // 401408  (b,h,w,i) sites
constexpr int kVotesF4 = kSITES * kCOUT * 4;       // 16,056,320 float4s
constexpr int kVotesFloats = kVotesF4 * 4;         // 64,225,280 floats
constexpr int kWPad = 17;                          // pad 16 -> 17 to spread LDS banks
}

__global__ __launch_bounds__(256) void classcaps_votes_kernel(
    const float4* __restrict__ poses,      // [kSITES*4] float4: (site*4 + m) is row m
    const float*  __restrict__ activations,// [kSITES]
    const float*  __restrict__ weight,     // [kCIN*kCOUT*16] = weight[i][o][n][p]
    const float*  __restrict__ xv,         // [kH*kW]
    const float*  __restrict__ yv,         // [kH*kW]
    float4*       __restrict__ out_votes,  // [kVotesF4]
    float*        __restrict__ out_acts)   // [kSITES]
{
    // Stage weight in LDS, padded: wsh[(i*kCOUT+o)*kWPad + n*4+p]
    __shared__ float wsh[kCIN * kCOUT * kWPad];    // 21.76 KB
    for (int t = threadIdx.x; t < kCIN * kCOUT * 16; t += 256) {
        const int mat = t >> 4;        // (i*kCOUT + o)
        const int e   = t & 15;        // n*4 + p
        wsh[mat * kWPad + e] = weight[t];
    }
    __syncthreads();

    const int tid0   = blockIdx.x * 256 + threadIdx.x;
    const int stride = gridDim.x * 256;

    // One thread per output float4: f -> (site, o, m); stores are lane-contiguous.
    for (int f = tid0; f < kVotesF4; f += stride) {
        const int m    = f & 3;
        const int so   = f >> 2;            // site * kCOUT + o
        const int o    = so % kCOUT;
        const int site = so / kCOUT;
        const int i    = site & (kCIN - 1);           // CIN = 32
        const int hw   = (site >> 5) % (kH * kW);     // site/32 = b*H*W + hw

        const float4 p = poses[site * 4 + m];          // row m of the pose matrix
        const float* wm = &wsh[(i * kCOUT + o) * kWPad];

        float4 r;
        r.x = p.x * wm[0] + p.y * wm[4] + p.z * wm[8]  + p.w * wm[12];
        r.y = p.x * wm[1] + p.y * wm[5] + p.z * wm[9]  + p.w * wm[13];
        r.z = p.x * wm[2] + p.y * wm[6] + p.z * wm[10] + p.w * wm[14];
        r.w = p.x * wm[3] + p.y * wm[7] + p.z * wm[11] + p.w * wm[15];

        if (m == 0)      r.w += xv[hw];
        else if (m == 1) r.w += yv[hw];

        out_votes[f] = r;
    }

    // Activations pass-through (second tuple output).
    for (int t = tid0; t < kSITES; t += stride)
        out_acts[t] = activations[t];
}

extern "C" void kernel_launch(void* const* d_in, const int* in_sizes, int n_in,
                              void* d_out, int out_size, void* d_ws, size_t ws_size,
                              hipStream_t stream) {
    const float4* poses       = (const float4*)d_in[0];
    const float*  activations = (const float*)d_in[1];
    const float*  weight      = (const float*)d_in[2];
    const float*  xv          = (const float*)d_in[3];
    const float*  yv          = (const float*)d_in[4];

    float* out       = (float*)d_out;
    float4* out_votes = (float4*)out;
    float*  out_acts  = out + kVotesFloats;

    dim3 grid(2048), block(256);
    classcaps_votes_kernel<<<grid, block, 0, stream>>>(
        poses, activations, weight, xv, yv, out_votes, out_acts);
}